// Round 2
// baseline (201.606 us; speedup 1.0000x reference)
//
#include <hip/hip_runtime.h>
#include <hip/hip_bf16.h>

#define ROWS 64
#define CELLS 64
#define CN_LEN 8
#define CV_LEN 16
#define EMB 768
#define HID 3072
#define NCELL 4096
#define L_CV 1024
#define ROW_TOK 1089  /* 1 cls + 64 cn + 1024 cv */

// ---- workspace layout (bytes) ----
#define OFF_ACC    0UL
#define OFF_FGATE  32UL
#define OFF_GPRE   64UL
#define ZERO_BYTES 16448UL                       /* acc8 + fgate + g_pre */
#define OFF_CNB    16448UL                       /* 4096x768 bf16 */
#define OFF_W1T    (OFF_CNB + 4096UL*768*2)      /* 3072x768 bf16 (transposed gate_w1) */
#define OFF_CST    (OFF_W1T + 3072UL*768*2)      /* 4096 int per-cell start */
#define OFF_CNT    (OFF_CST + 4096UL*4)          /* 64 int per-row count */

typedef __attribute__((ext_vector_type(8))) short bf16x8;
typedef __attribute__((ext_vector_type(4))) float f32x4;

static __device__ __forceinline__ short f2bf(float x) {
  unsigned u = __float_as_uint(x);
  unsigned r = (u + 0x7fffu + ((u >> 16) & 1u)) >> 16;
  return (short)r;
}

static __device__ __forceinline__ void gload16(const void* g, void* l) {
  __builtin_amdgcn_global_load_lds(
      (const __attribute__((address_space(1))) unsigned*)g,
      (__attribute__((address_space(3))) unsigned*)l, 16, 0, 0);
}

// ---------- fgate: per-type fuse-MLP scalar (8 types only) ----------
__global__ __launch_bounds__(256) void k_fgate_acc(
    const float* __restrict__ type_emb, const float* __restrict__ fuse_w1,
    const float* __restrict__ fuse_b1, const float* __restrict__ fuse_w2,
    float* __restrict__ acc8) {
  __shared__ float te[8 * EMB];
  const int tid = threadIdx.x;
  for (int i = tid; i < 8 * EMB; i += 256) te[i] = type_emb[i];
  __syncthreads();
  const int t = tid >> 5, hl = tid & 31;
  const int h = blockIdx.x * 32 + hl;
  float a = fuse_b1[h];
  const float* w1c = fuse_w1 + h;
  const float* tr = te + t * EMB;
  for (int e = 0; e < EMB; e++) a += tr[e] * w1c[(size_t)e * HID];
  float v = fmaxf(a, 0.f) * fuse_w2[h];
  #pragma unroll
  for (int m = 1; m < 32; m <<= 1) v += __shfl_xor(v, m);
  if (hl == 0) atomicAdd(&acc8[t], v);
}

__global__ void k_fgate_fin(const float* __restrict__ acc8,
                            const float* __restrict__ fuse_b2,
                            float* __restrict__ fgate) {
  const int t = threadIdx.x;
  if (t < 8) fgate[t] = 1.f / (1.f + expf(-(acc8[t] + fuse_b2[0])));
}

// ---------- transpose + bf16-convert gate_w1 [768xH] -> w1t [Hx768] ----------
__global__ __launch_bounds__(256) void k_w1t(const float* __restrict__ w1,
                                             short* __restrict__ w1t) {
  __shared__ float tile[32][33];
  const int bx = blockIdx.x, by = blockIdx.y;  // bx: h tile, by: e tile
  const int tid = threadIdx.x;
  #pragma unroll
  for (int i = 0; i < 4; i++) {
    int idx = tid + i * 256;
    int rr = idx >> 5, cc = idx & 31;
    tile[rr][cc] = w1[(size_t)(by * 32 + rr) * HID + bx * 32 + cc];
  }
  __syncthreads();
  #pragma unroll
  for (int i = 0; i < 4; i++) {
    int idx = tid + i * 256;
    int rr = idx >> 5, cc = idx & 31;
    w1t[(size_t)(bx * 32 + rr) * EMB + by * 32 + cc] = f2bf(tile[cc][rr]);
  }
}

// ---------- cn_e: masked avg + type gate; write out cn region + cls ----------
__global__ __launch_bounds__(192) void k_cn(
    const int* __restrict__ cn_ids, const int* __restrict__ cn_mask,
    const int* __restrict__ c_types, const float* __restrict__ word_emb,
    const float* __restrict__ type_emb, const float* __restrict__ cls_w,
    const float* __restrict__ fgate, short* __restrict__ cnb,
    float* __restrict__ out) {
  const int n = blockIdx.x, tid = threadIdx.x;
  const int row = n >> 6, cell = n & 63;
  const int* ids = cn_ids + n * CN_LEN;
  const int* msk = cn_mask + n * CN_LEN;
  float4 s = {0.f, 0.f, 0.f, 0.f};
  int cnt = 0;
  #pragma unroll
  for (int j = 0; j < CN_LEN; j++) {
    if (msk[j]) {
      cnt++;
      const float4 v = *(const float4*)&word_emb[(size_t)ids[j] * EMB + tid * 4];
      s.x += v.x; s.y += v.y; s.z += v.z; s.w += v.w;
    }
  }
  const float inv = 1.f / (float)cnt;
  const int t = c_types[n];
  const float fg = fgate[t];
  const float4 d = *(const float4*)&type_emb[(size_t)t * EMB + tid * 4];
  float4 c;
  c.x = s.x * inv + d.x * fg;
  c.y = s.y * inv + d.y * fg;
  c.z = s.z * inv + d.z * fg;
  c.w = s.w * inv + d.w * fg;
  short4 b;
  b.x = f2bf(c.x); b.y = f2bf(c.y); b.z = f2bf(c.z); b.w = f2bf(c.w);
  *(short4*)&cnb[(size_t)n * EMB + tid * 4] = b;
  *(float4*)&out[(size_t)row * ROW_TOK * EMB + (size_t)(1 + cell) * EMB + tid * 4] = c;
  if (cell == 0)
    *(float4*)&out[(size_t)row * ROW_TOK * EMB + tid * 4] =
        *(const float4*)&cls_w[tid * 4];
}

// ---------- gate MLP: m97-style 128x128 bf16 MFMA GEMM, fused epilogue ----------
__global__ __launch_bounds__(256) void k_gate_gemm(
    const short* __restrict__ cnb, const short* __restrict__ w1t,
    const float* __restrict__ gate_b1, const float* __restrict__ gate_w2,
    float* __restrict__ g_pre) {
  __shared__ short Asub[128 * 32];
  __shared__ short Bsub[128 * 32];
  const int tid = threadIdx.x;
  const int n0 = blockIdx.x * 128;
  const int h0 = blockIdx.y * 128;
  const int lane = tid & 63, w = tid >> 6;
  const int wr = w >> 1, wc = w & 1;
  const int r = lane & 15, g = lane >> 4;
  f32x4 acc[4][4];
  #pragma unroll
  for (int a = 0; a < 4; a++)
    #pragma unroll
    for (int b = 0; b < 4; b++) acc[a][b] = (f32x4)0.f;

  const int c0 = tid, c1 = tid + 256;
  const int r0 = c0 >> 2, k0 = (c0 & 3) * 8;
  const int r1 = c1 >> 2, k1 = (c1 & 3) * 8;

  for (int kk = 0; kk < EMB; kk += 32) {
    gload16(cnb + (size_t)(n0 + r0) * EMB + kk + k0, Asub + c0 * 8);
    gload16(cnb + (size_t)(n0 + r1) * EMB + kk + k1, Asub + c1 * 8);
    gload16(w1t + (size_t)(h0 + r0) * EMB + kk + k0, Bsub + c0 * 8);
    gload16(w1t + (size_t)(h0 + r1) * EMB + kk + k1, Bsub + c1 * 8);
    __syncthreads();
    bf16x8 fa[4], fb[4];
    #pragma unroll
    for (int fm = 0; fm < 4; fm++) {
      const short* ap = &Asub[(wr * 64 + fm * 16 + r) * 32];
      short4 lo = *(const short4*)(ap + 4 * g);
      short4 hi = *(const short4*)(ap + 16 + 4 * g);
      fa[fm] = (bf16x8){lo.x, lo.y, lo.z, lo.w, hi.x, hi.y, hi.z, hi.w};
    }
    #pragma unroll
    for (int fn = 0; fn < 4; fn++) {
      const short* bp = &Bsub[(wc * 64 + fn * 16 + r) * 32];
      short4 lo = *(const short4*)(bp + 4 * g);
      short4 hi = *(const short4*)(bp + 16 + 4 * g);
      fb[fn] = (bf16x8){lo.x, lo.y, lo.z, lo.w, hi.x, hi.y, hi.z, hi.w};
    }
    #pragma unroll
    for (int fm = 0; fm < 4; fm++)
      #pragma unroll
      for (int fn = 0; fn < 4; fn++)
        acc[fm][fn] = __builtin_amdgcn_mfma_f32_16x16x32_bf16(
            fa[fm], fb[fn], acc[fm][fn], 0, 0, 0);
    __syncthreads();
  }

  // epilogue: rowsum over this block's 128 h of relu(v + b1[h]) * w2[h]
  #pragma unroll
  for (int fm = 0; fm < 4; fm++) {
    float rs[4] = {0.f, 0.f, 0.f, 0.f};
    #pragma unroll
    for (int fn = 0; fn < 4; fn++) {
      const int h = h0 + wc * 64 + fn * 16 + r;
      const float bv = gate_b1[h];
      const float wv = gate_w2[h];
      #pragma unroll
      for (int q = 0; q < 4; q++) {
        float v = acc[fm][fn][q] + bv;
        rs[q] += fmaxf(v, 0.f) * wv;
      }
    }
    #pragma unroll
    for (int q = 0; q < 4; q++)
      #pragma unroll
      for (int m = 1; m < 16; m <<= 1) rs[q] += __shfl_xor(rs[q], m);
    if (r == 0) {
      #pragma unroll
      for (int q = 0; q < 4; q++)
        atomicAdd(&g_pre[n0 + wr * 64 + fm * 16 + g * 4 + q], rs[q]);
    }
  }
}

// ---------- per-row prefix sum: per-cell start offsets + row counts ----------
__global__ __launch_bounds__(256) void k_prefix(const int* __restrict__ cv_mask,
                                                int* __restrict__ cstart,
                                                int* __restrict__ cnt) {
  const int row = blockIdx.x, tid = threadIdx.x;
  __shared__ int ssum[256];
  int m[4];
  const int base = row * L_CV + tid * 4;
  int s = 0;
  #pragma unroll
  for (int i = 0; i < 4; i++) { m[i] = cv_mask[base + i]; s += m[i]; }
  ssum[tid] = s;
  __syncthreads();
  for (int off = 1; off < 256; off <<= 1) {
    int v = (tid >= off) ? ssum[tid - off] : 0;
    __syncthreads();
    ssum[tid] += v;
    __syncthreads();
  }
  if ((tid & 3) == 0) cstart[row * CELLS + (tid >> 2)] = ssum[tid] - s;
  if (tid == 255) cnt[row] = ssum[255];
}

// ---------- cv compute: one block per cell, compact writes ----------
__global__ __launch_bounds__(192) void k_cv_cell(
    const int* __restrict__ cv_ids, const int* __restrict__ cv_mask,
    const int* __restrict__ cstart, const float* __restrict__ word_emb,
    const float* __restrict__ g_pre, const float* __restrict__ gate_b2,
    float* __restrict__ out) {
  const int cell = blockIdx.x, row = blockIdx.y, tid = threadIdx.x;
  const int n = row * CELLS + cell;
  const size_t rbase = (size_t)row * ROW_TOK * EMB;
  const float4 cn = *(const float4*)&out[rbase + (size_t)(1 + cell) * EMB + tid * 4];
  const float gg = 1.f / (1.f + expf(-(g_pre[n] + gate_b2[0])));
  float4 cg;
  cg.x = cn.x * gg; cg.y = cn.y * gg; cg.z = cn.z * gg; cg.w = cn.w * gg;
  const int* ids = cv_ids + n * CV_LEN;
  const int* msk = cv_mask + n * CV_LEN;
  int pos = cstart[n];
  #pragma unroll
  for (int j = 0; j < CV_LEN; j++) {
    if (msk[j]) {
      const float4 we = *(const float4*)&word_emb[(size_t)ids[j] * EMB + tid * 4];
      float4 v;
      v.x = we.x + cg.x; v.y = we.y + cg.y; v.z = we.z + cg.z; v.w = we.w + cg.w;
      *(float4*)&out[rbase + (size_t)(65 + pos) * EMB + tid * 4] = v;
      pos++;
    }
  }
}

// ---------- cv tail: zero-fill slots past each row's count ----------
__global__ __launch_bounds__(192) void k_cv_fill(const int* __restrict__ cnt,
                                                 float* __restrict__ out) {
  const int k = blockIdx.x, row = blockIdx.y, tid = threadIdx.x;
  if (k < cnt[row]) return;
  const float4 z = {0.f, 0.f, 0.f, 0.f};
  *(float4*)&out[(size_t)row * ROW_TOK * EMB + (size_t)(65 + k) * EMB + tid * 4] = z;
}

extern "C" void kernel_launch(void* const* d_in, const int* in_sizes, int n_in,
                              void* d_out, int out_size, void* d_ws, size_t ws_size,
                              hipStream_t stream) {
  const int* cn_ids    = (const int*)d_in[0];
  const int* cn_mask   = (const int*)d_in[1];
  const int* c_types   = (const int*)d_in[2];
  const int* cv_ids    = (const int*)d_in[3];
  const int* cv_mask   = (const int*)d_in[4];
  const float* word_emb = (const float*)d_in[5];
  const float* type_emb = (const float*)d_in[6];
  const float* fuse_w1  = (const float*)d_in[7];
  const float* fuse_b1  = (const float*)d_in[8];
  const float* fuse_w2  = (const float*)d_in[9];
  const float* fuse_b2  = (const float*)d_in[10];
  const float* gate_w1  = (const float*)d_in[11];
  const float* gate_b1  = (const float*)d_in[12];
  const float* gate_w2  = (const float*)d_in[13];
  const float* gate_b2  = (const float*)d_in[14];
  const float* cls_w    = (const float*)d_in[15];

  char* ws = (char*)d_ws;
  float* acc8  = (float*)(ws + OFF_ACC);
  float* fgate = (float*)(ws + OFF_FGATE);
  float* gpre  = (float*)(ws + OFF_GPRE);
  short* cnb   = (short*)(ws + OFF_CNB);
  short* w1t   = (short*)(ws + OFF_W1T);
  int*   cst   = (int*)(ws + OFF_CST);
  int*   cntp  = (int*)(ws + OFF_CNT);
  float* out   = (float*)d_out;

  hipMemsetAsync(ws, 0, ZERO_BYTES, stream);
  k_fgate_acc<<<96, 256, 0, stream>>>(type_emb, fuse_w1, fuse_b1, fuse_w2, acc8);
  k_fgate_fin<<<1, 64, 0, stream>>>(acc8, fuse_b2, fgate);
  k_w1t<<<dim3(96, 24), 256, 0, stream>>>(gate_w1, w1t);
  k_cn<<<NCELL, 192, 0, stream>>>(cn_ids, cn_mask, c_types, word_emb, type_emb,
                                  cls_w, fgate, cnb, out);
  k_gate_gemm<<<dim3(32, 24), 256, 0, stream>>>(cnb, w1t, gate_b1, gate_w2, gpre);
  k_prefix<<<64, 256, 0, stream>>>(cv_mask, cst, cntp);
  k_cv_cell<<<dim3(CELLS, ROWS), 192, 0, stream>>>(cv_ids, cv_mask, cst, word_emb,
                                                   gpre, gate_b2, out);
  k_cv_fill<<<dim3(L_CV, ROWS), 192, 0, stream>>>(cntp, out);
}

// Round 3
// 145.984 us; speedup vs baseline: 1.3810x; 1.3810x over previous
//
#include <hip/hip_runtime.h>
#include <hip/hip_bf16.h>

#define ROWS 64
#define CELLS 64
#define CN_LEN 8
#define CV_LEN 16
#define EMB 768
#define HID 3072
#define NCELL 4096
#define L_CV 1024
#define ROW_TOK 1089  /* 1 cls + 64 cn + 1024 cv */
#define HBLK 24       /* 3072/128 h-blocks in gate GEMM */

// ---- workspace layout (bytes), no zero-init required anywhere ----
#define OFF_FPART 0UL                             /* 96*8 f32 fgate partials */
#define OFF_FGATE (OFF_FPART + 96UL*8*4)          /* 8 f32 */
#define OFF_GPART (OFF_FGATE + 64UL)              /* 24*4096 f32 gemm partials */
#define OFF_GFULL (OFF_GPART + 24UL*4096*4)       /* 4096 f32 sigmoid(g) */
#define OFF_CNB   (OFF_GFULL + 4096UL*4)          /* 4096x768 bf16 */
#define OFF_W1T   (OFF_CNB + 4096UL*768*2)        /* 3072x768 bf16 (gate_w1^T) */
#define OFF_CST   (OFF_W1T + 3072UL*768*2)        /* 4096 int per-cell start */
#define OFF_CNT   (OFF_CST + 4096UL*4)            /* 64 int per-row count */

typedef __attribute__((ext_vector_type(8))) short bf16x8;
typedef __attribute__((ext_vector_type(4))) float f32x4;

static __device__ __forceinline__ short f2bf(float x) {
  unsigned u = __float_as_uint(x);
  unsigned r = (u + 0x7fffu + ((u >> 16) & 1u)) >> 16;
  return (short)r;
}

static __device__ __forceinline__ void gload16(const void* g, void* l) {
  __builtin_amdgcn_global_load_lds(
      (const __attribute__((address_space(1))) unsigned*)g,
      (__attribute__((address_space(3))) unsigned*)l, 16, 0, 0);
}

// ---------- fgate partials: per-type fuse-MLP (8 types only) ----------
__global__ __launch_bounds__(256) void k_fgate_acc(
    const float* __restrict__ type_emb, const float* __restrict__ fuse_w1,
    const float* __restrict__ fuse_b1, const float* __restrict__ fuse_w2,
    float* __restrict__ fpart) {
  __shared__ float te[8 * EMB];
  const int tid = threadIdx.x;
  for (int i = tid; i < 8 * EMB; i += 256) te[i] = type_emb[i];
  __syncthreads();
  const int t = tid >> 5, hl = tid & 31;
  const int h = blockIdx.x * 32 + hl;
  float a = fuse_b1[h];
  const float* w1c = fuse_w1 + h;
  const float* tr = te + t * EMB;
  for (int e = 0; e < EMB; e++) a += tr[e] * w1c[(size_t)e * HID];
  float v = fmaxf(a, 0.f) * fuse_w2[h];
  #pragma unroll
  for (int m = 1; m < 32; m <<= 1) v += __shfl_xor(v, m);
  if (hl == 0) fpart[blockIdx.x * 8 + t] = v;  // each slot written exactly once
}

// ---------- transpose + bf16 gate_w1 -> w1t; block(0,0) finalizes fgate ----------
__global__ __launch_bounds__(256) void k_w1t(const float* __restrict__ w1,
                                             short* __restrict__ w1t,
                                             const float* __restrict__ fpart,
                                             const float* __restrict__ fuse_b2,
                                             float* __restrict__ fgate) {
  __shared__ float tile[32][33];
  const int bx = blockIdx.x, by = blockIdx.y;  // bx: h tile, by: e tile
  const int tid = threadIdx.x;
  if (bx == 0 && by == 0 && tid < 8) {
    float s = fuse_b2[0];
    for (int j = 0; j < 96; j++) s += fpart[j * 8 + tid];
    fgate[tid] = 1.f / (1.f + expf(-s));
  }
  #pragma unroll
  for (int i = 0; i < 4; i++) {
    int idx = tid + i * 256;
    int rr = idx >> 5, cc = idx & 31;
    tile[rr][cc] = w1[(size_t)(by * 32 + rr) * HID + bx * 32 + cc];
  }
  __syncthreads();
  #pragma unroll
  for (int i = 0; i < 4; i++) {
    int idx = tid + i * 256;
    int rr = idx >> 5, cc = idx & 31;
    w1t[(size_t)(bx * 32 + rr) * EMB + by * 32 + cc] = f2bf(tile[cc][rr]);
  }
}

// ---------- cn_e: masked avg + type gate; write out cn region + cls ----------
__global__ __launch_bounds__(192) void k_cn(
    const int* __restrict__ cn_ids, const int* __restrict__ cn_mask,
    const int* __restrict__ c_types, const float* __restrict__ word_emb,
    const float* __restrict__ type_emb, const float* __restrict__ cls_w,
    const float* __restrict__ fgate, short* __restrict__ cnb,
    float* __restrict__ out) {
  const int n = blockIdx.x, tid = threadIdx.x;
  const int row = n >> 6, cell = n & 63;
  const int* ids = cn_ids + n * CN_LEN;
  const int* msk = cn_mask + n * CN_LEN;
  float4 s = {0.f, 0.f, 0.f, 0.f};
  int cnt = 0;
  #pragma unroll
  for (int j = 0; j < CN_LEN; j++) {
    if (msk[j]) {
      cnt++;
      const float4 v = *(const float4*)&word_emb[(size_t)ids[j] * EMB + tid * 4];
      s.x += v.x; s.y += v.y; s.z += v.z; s.w += v.w;
    }
  }
  const float inv = 1.f / (float)cnt;
  const int t = c_types[n];
  const float fg = fgate[t];
  const float4 d = *(const float4*)&type_emb[(size_t)t * EMB + tid * 4];
  float4 c;
  c.x = s.x * inv + d.x * fg;
  c.y = s.y * inv + d.y * fg;
  c.z = s.z * inv + d.z * fg;
  c.w = s.w * inv + d.w * fg;
  short4 b;
  b.x = f2bf(c.x); b.y = f2bf(c.y); b.z = f2bf(c.z); b.w = f2bf(c.w);
  *(short4*)&cnb[(size_t)n * EMB + tid * 4] = b;
  *(float4*)&out[(size_t)row * ROW_TOK * EMB + (size_t)(1 + cell) * EMB + tid * 4] = c;
  if (cell == 0)
    *(float4*)&out[(size_t)row * ROW_TOK * EMB + tid * 4] =
        *(const float4*)&cls_w[tid * 4];
}

// ---------- gate MLP GEMM: 128x128 tile, contiguous-k fragments (b128, 0-conflict) ----------
__global__ __launch_bounds__(256) void k_gate_gemm(
    const short* __restrict__ cnb, const short* __restrict__ w1t,
    const float* __restrict__ gate_b1, const float* __restrict__ gate_w2,
    float* __restrict__ gpart) {
  __shared__ short Asub[128 * 32];
  __shared__ short Bsub[128 * 32];
  const int tid = threadIdx.x;
  const int n0 = blockIdx.x * 128;
  const int h0 = blockIdx.y * 128;
  const int lane = tid & 63, w = tid >> 6;
  const int wr = w >> 1, wc = w & 1;
  const int r = lane & 15, g = lane >> 4;
  f32x4 acc[4][4];
  #pragma unroll
  for (int a = 0; a < 4; a++)
    #pragma unroll
    for (int b = 0; b < 4; b++) acc[a][b] = (f32x4)0.f;

  // staging slot s (16B): row = s>>2, chunk = s&3 -> global row*64B + chunk*16B
  const int s0 = tid, s1 = tid + 256;
  const int ar0 = s0 >> 2, ac0 = (s0 & 3) * 8;
  const int ar1 = s1 >> 2, ac1 = (s1 & 3) * 8;

  for (int kk = 0; kk < EMB; kk += 32) {
    gload16(cnb + (size_t)(n0 + ar0) * EMB + kk + ac0, Asub + s0 * 8);
    gload16(cnb + (size_t)(n0 + ar1) * EMB + kk + ac1, Asub + s1 * 8);
    gload16(w1t + (size_t)(h0 + ar0) * EMB + kk + ac0, Bsub + s0 * 8);
    gload16(w1t + (size_t)(h0 + ar1) * EMB + kk + ac1, Bsub + s1 * 8);
    __syncthreads();
    bf16x8 fa[4], fb[4];
    #pragma unroll
    for (int fm = 0; fm < 4; fm++)
      fa[fm] = *(const bf16x8*)&Asub[(wr * 64 + fm * 16 + r) * 32 + g * 8];
    #pragma unroll
    for (int fn = 0; fn < 4; fn++)
      fb[fn] = *(const bf16x8*)&Bsub[(wc * 64 + fn * 16 + r) * 32 + g * 8];
    #pragma unroll
    for (int fm = 0; fm < 4; fm++)
      #pragma unroll
      for (int fn = 0; fn < 4; fn++)
        acc[fm][fn] = __builtin_amdgcn_mfma_f32_16x16x32_bf16(
            fa[fm], fb[fn], acc[fm][fn], 0, 0, 0);
    __syncthreads();
  }

  // epilogue: rowsum over this block's 128 h of relu(v + b1[h]) * w2[h]
  float rsum[4][4];
  #pragma unroll
  for (int fm = 0; fm < 4; fm++) {
    float rs[4] = {0.f, 0.f, 0.f, 0.f};
    #pragma unroll
    for (int fn = 0; fn < 4; fn++) {
      const int h = h0 + wc * 64 + fn * 16 + r;
      const float bv = gate_b1[h];
      const float wv = gate_w2[h];
      #pragma unroll
      for (int q = 0; q < 4; q++)
        rs[q] += fmaxf(acc[fm][fn][q] + bv, 0.f) * wv;
    }
    #pragma unroll
    for (int q = 0; q < 4; q++) {
      #pragma unroll
      for (int m = 1; m < 16; m <<= 1) rs[q] += __shfl_xor(rs[q], m);
      rsum[fm][q] = rs[q];
    }
  }
  // combine wc=0/1 waves via LDS (Asub is free), write partial once per n
  float* red = (float*)Asub;
  __syncthreads();
  if (wc == 1 && r == 0) {
    #pragma unroll
    for (int fm = 0; fm < 4; fm++)
      #pragma unroll
      for (int q = 0; q < 4; q++)
        red[wr * 64 + fm * 16 + g * 4 + q] = rsum[fm][q];
  }
  __syncthreads();
  if (wc == 0 && r == 0) {
    #pragma unroll
    for (int fm = 0; fm < 4; fm++)
      #pragma unroll
      for (int q = 0; q < 4; q++) {
        const int i = wr * 64 + fm * 16 + g * 4 + q;
        gpart[(size_t)blockIdx.y * NCELL + n0 + i] = rsum[fm][q] + red[i];
      }
  }
}

// ---------- finalize g: sum 24 partials + sigmoid ----------
__global__ __launch_bounds__(256) void k_gfin(const float* __restrict__ gpart,
                                              const float* __restrict__ gate_b2,
                                              float* __restrict__ gfull) {
  const int n = blockIdx.x * 256 + threadIdx.x;
  float s = gate_b2[0];
  #pragma unroll
  for (int j = 0; j < HBLK; j++) s += gpart[(size_t)j * NCELL + n];
  gfull[n] = 1.f / (1.f + expf(-s));
}

// ---------- per-row prefix sum: per-cell start offsets + row counts ----------
__global__ __launch_bounds__(256) void k_prefix(const int* __restrict__ cv_mask,
                                                int* __restrict__ cstart,
                                                int* __restrict__ cnt) {
  const int row = blockIdx.x, tid = threadIdx.x;
  __shared__ int ssum[256];
  int m[4];
  const int base = row * L_CV + tid * 4;
  int s = 0;
  #pragma unroll
  for (int i = 0; i < 4; i++) { m[i] = cv_mask[base + i]; s += m[i]; }
  ssum[tid] = s;
  __syncthreads();
  for (int off = 1; off < 256; off <<= 1) {
    int v = (tid >= off) ? ssum[tid - off] : 0;
    __syncthreads();
    ssum[tid] += v;
    __syncthreads();
  }
  if ((tid & 3) == 0) cstart[row * CELLS + (tid >> 2)] = ssum[tid] - s;
  if (tid == 255) cnt[row] = ssum[255];
}

// ---------- cv region: bx<64 compute cell tokens; bx>=64 zero-fill tail ----------
__global__ __launch_bounds__(192) void k_cv_cell(
    const int* __restrict__ cv_ids, const int* __restrict__ cv_mask,
    const int* __restrict__ cstart, const int* __restrict__ cnt,
    const float* __restrict__ word_emb, const float* __restrict__ gfull,
    float* __restrict__ out) {
  const int bx = blockIdx.x, row = blockIdx.y, tid = threadIdx.x;
  const size_t rbase = (size_t)row * ROW_TOK * EMB;
  if (bx >= CELLS) {
    const int base = cnt[row] + (bx - CELLS) * 8;
    const float4 z = {0.f, 0.f, 0.f, 0.f};
    #pragma unroll
    for (int i = 0; i < 8; i++) {
      const int k = base + i;
      if (k < L_CV)
        *(float4*)&out[rbase + (size_t)(65 + k) * EMB + tid * 4] = z;
    }
    return;
  }
  const int cell = bx;
  const int n = row * CELLS + cell;
  const float4 cn = *(const float4*)&out[rbase + (size_t)(1 + cell) * EMB + tid * 4];
  const float gg = gfull[n];
  float4 cg;
  cg.x = cn.x * gg; cg.y = cn.y * gg; cg.z = cn.z * gg; cg.w = cn.w * gg;
  const int* ids = cv_ids + n * CV_LEN;
  const int* msk = cv_mask + n * CV_LEN;
  int pos = cstart[n];
  #pragma unroll
  for (int j = 0; j < CV_LEN; j++) {
    if (msk[j]) {
      const float4 we = *(const float4*)&word_emb[(size_t)ids[j] * EMB + tid * 4];
      float4 v;
      v.x = we.x + cg.x; v.y = we.y + cg.y; v.z = we.z + cg.z; v.w = we.w + cg.w;
      *(float4*)&out[rbase + (size_t)(65 + pos) * EMB + tid * 4] = v;
      pos++;
    }
  }
}

extern "C" void kernel_launch(void* const* d_in, const int* in_sizes, int n_in,
                              void* d_out, int out_size, void* d_ws, size_t ws_size,
                              hipStream_t stream) {
  const int* cn_ids    = (const int*)d_in[0];
  const int* cn_mask   = (const int*)d_in[1];
  const int* c_types   = (const int*)d_in[2];
  const int* cv_ids    = (const int*)d_in[3];
  const int* cv_mask   = (const int*)d_in[4];
  const float* word_emb = (const float*)d_in[5];
  const float* type_emb = (const float*)d_in[6];
  const float* fuse_w1  = (const float*)d_in[7];
  const float* fuse_b1  = (const float*)d_in[8];
  const float* fuse_w2  = (const float*)d_in[9];
  const float* fuse_b2  = (const float*)d_in[10];
  const float* gate_w1  = (const float*)d_in[11];
  const float* gate_b1  = (const float*)d_in[12];
  const float* gate_w2  = (const float*)d_in[13];
  const float* gate_b2  = (const float*)d_in[14];
  const float* cls_w    = (const float*)d_in[15];

  char* ws = (char*)d_ws;
  float* fpart = (float*)(ws + OFF_FPART);
  float* fgate = (float*)(ws + OFF_FGATE);
  float* gpart = (float*)(ws + OFF_GPART);
  float* gfull = (float*)(ws + OFF_GFULL);
  short* cnb   = (short*)(ws + OFF_CNB);
  short* w1t   = (short*)(ws + OFF_W1T);
  int*   cst   = (int*)(ws + OFF_CST);
  int*   cntp  = (int*)(ws + OFF_CNT);
  float* out   = (float*)d_out;

  k_fgate_acc<<<96, 256, 0, stream>>>(type_emb, fuse_w1, fuse_b1, fuse_w2, fpart);
  k_w1t<<<dim3(96, 24), 256, 0, stream>>>(gate_w1, w1t, fpart, fuse_b2, fgate);
  k_cn<<<NCELL, 192, 0, stream>>>(cn_ids, cn_mask, c_types, word_emb, type_emb,
                                  cls_w, fgate, cnb, out);
  k_gate_gemm<<<dim3(32, HBLK), 256, 0, stream>>>(cnb, w1t, gate_b1, gate_w2, gpart);
  k_gfin<<<16, 256, 0, stream>>>(gpart, gate_b2, gfull);
  k_prefix<<<64, 256, 0, stream>>>(cv_mask, cst, cntp);
  k_cv_cell<<<dim3(CELLS + 128, ROWS), 192, 0, stream>>>(cv_ids, cv_mask, cst,
                                                         cntp, word_emb, gfull, out);
}

// Round 4
// 125.245 us; speedup vs baseline: 1.6097x; 1.1656x over previous
//
#include <hip/hip_runtime.h>
#include <hip/hip_bf16.h>

#define ROWS 64
#define CELLS 64
#define CN_LEN 8
#define CV_LEN 16
#define EMB 768
#define HID 3072
#define NCELL 4096
#define L_CV 1024
#define ROW_TOK 1089  /* 1 cls + 64 cn + 1024 cv */
#define HBLK 24       /* 3072/128 h-blocks in gate GEMM */

// ---- workspace layout (bytes), no zero-init required anywhere ----
#define OFF_FPART 0UL                             /* 96*8 f32 fgate partials */
#define OFF_FGATE (OFF_FPART + 96UL*8*4)          /* 8 f32 */
#define OFF_GPART (OFF_FGATE + 64UL)              /* 24*4096 f32 gemm partials */
#define OFF_CNB   (OFF_GPART + 24UL*4096*4)       /* 4096x768 bf16 */
#define OFF_W1T   (OFF_CNB + 4096UL*768*2)        /* 3072x768 bf16 (gate_w1^T) */
#define OFF_CST   (OFF_W1T + 3072UL*768*2)        /* 4096 int per-cell start */
#define OFF_CNT   (OFF_CST + 4096UL*4)            /* 64 int per-row count */

typedef __attribute__((ext_vector_type(8))) short bf16x8;
typedef __attribute__((ext_vector_type(4))) float f32x4;

static __device__ __forceinline__ short f2bf(float x) {
  unsigned u = __float_as_uint(x);
  unsigned r = (u + 0x7fffu + ((u >> 16) & 1u)) >> 16;
  return (short)r;
}

static __device__ __forceinline__ void gload16(const void* g, void* l) {
  __builtin_amdgcn_global_load_lds(
      (const __attribute__((address_space(1))) unsigned*)g,
      (__attribute__((address_space(3))) unsigned*)l, 16, 0, 0);
}

// ---------- fgate partials: 8-type register reuse, w1 read once ----------
__global__ __launch_bounds__(512) void k_fgate_acc(
    const float* __restrict__ type_emb, const float* __restrict__ fuse_w1,
    const float* __restrict__ fuse_b1, const float* __restrict__ fuse_w2,
    float* __restrict__ fpart) {
  __shared__ float te[8 * EMB];      // 24 KB
  __shared__ float red[16][8][33];   // [egroup][type][h-lane]
  const int tid = threadIdx.x;
  for (int i = tid; i < 8 * EMB; i += 512) te[i] = type_emb[i];
  __syncthreads();
  const int hl = tid & 31, eg = tid >> 5;  // eg in 0..15, 48 e's each
  const int h = blockIdx.x * 32 + hl;
  float acc[8] = {0.f, 0.f, 0.f, 0.f, 0.f, 0.f, 0.f, 0.f};
  const float* wp = fuse_w1 + h;
  #pragma unroll 4
  for (int i = 0; i < 48; i++) {
    const int e = eg * 48 + i;
    const float wv = wp[(size_t)e * HID];
    #pragma unroll
    for (int t = 0; t < 8; t++) acc[t] += te[t * EMB + e] * wv;
  }
  #pragma unroll
  for (int t = 0; t < 8; t++) red[eg][t][hl] = acc[t];
  __syncthreads();
  if (tid < 256) {
    const int t = tid >> 5, h2 = tid & 31;
    float a = fuse_b1[blockIdx.x * 32 + h2];
    #pragma unroll
    for (int e2 = 0; e2 < 16; e2++) a += red[e2][t][h2];
    float v = fmaxf(a, 0.f) * fuse_w2[blockIdx.x * 32 + h2];
    #pragma unroll
    for (int m = 1; m < 32; m <<= 1) v += __shfl_xor(v, m);
    if (h2 == 0) fpart[blockIdx.x * 8 + t] = v;  // each slot written once
  }
}

// ---------- transpose + bf16 gate_w1 -> w1t; block(0,0) finalizes fgate ----------
__global__ __launch_bounds__(256) void k_w1t(const float* __restrict__ w1,
                                             short* __restrict__ w1t,
                                             const float* __restrict__ fpart,
                                             const float* __restrict__ fuse_b2,
                                             float* __restrict__ fgate) {
  __shared__ float tile[32][33];
  const int bx = blockIdx.x, by = blockIdx.y;  // bx: h tile, by: e tile
  const int tid = threadIdx.x;
  if (bx == 0 && by == 0 && tid < 8) {
    float s = fuse_b2[0];
    for (int j = 0; j < 96; j++) s += fpart[j * 8 + tid];
    fgate[tid] = 1.f / (1.f + expf(-s));
  }
  #pragma unroll
  for (int i = 0; i < 4; i++) {
    int idx = tid + i * 256;
    int rr = idx >> 5, cc = idx & 31;
    tile[rr][cc] = w1[(size_t)(by * 32 + rr) * HID + bx * 32 + cc];
  }
  __syncthreads();
  #pragma unroll
  for (int i = 0; i < 4; i++) {
    int idx = tid + i * 256;
    int rr = idx >> 5, cc = idx & 31;
    w1t[(size_t)(bx * 32 + rr) * EMB + by * 32 + cc] = f2bf(tile[cc][rr]);
  }
}

// ---------- cn_e: masked avg + type gate; write out cn region + cls ----------
__global__ __launch_bounds__(192) void k_cn(
    const int* __restrict__ cn_ids, const int* __restrict__ cn_mask,
    const int* __restrict__ c_types, const float* __restrict__ word_emb,
    const float* __restrict__ type_emb, const float* __restrict__ cls_w,
    const float* __restrict__ fgate, short* __restrict__ cnb,
    float* __restrict__ out) {
  const int n = blockIdx.x, tid = threadIdx.x;
  const int row = n >> 6, cell = n & 63;
  const int* ids = cn_ids + n * CN_LEN;
  const int* msk = cn_mask + n * CN_LEN;
  float4 s = {0.f, 0.f, 0.f, 0.f};
  int cnt = 0;
  #pragma unroll
  for (int j = 0; j < CN_LEN; j++) {
    if (msk[j]) {
      cnt++;
      const float4 v = *(const float4*)&word_emb[(size_t)ids[j] * EMB + tid * 4];
      s.x += v.x; s.y += v.y; s.z += v.z; s.w += v.w;
    }
  }
  const float inv = 1.f / (float)cnt;
  const int t = c_types[n];
  const float fg = fgate[t];
  const float4 d = *(const float4*)&type_emb[(size_t)t * EMB + tid * 4];
  float4 c;
  c.x = s.x * inv + d.x * fg;
  c.y = s.y * inv + d.y * fg;
  c.z = s.z * inv + d.z * fg;
  c.w = s.w * inv + d.w * fg;
  short4 b;
  b.x = f2bf(c.x); b.y = f2bf(c.y); b.z = f2bf(c.z); b.w = f2bf(c.w);
  *(short4*)&cnb[(size_t)n * EMB + tid * 4] = b;
  *(float4*)&out[(size_t)row * ROW_TOK * EMB + (size_t)(1 + cell) * EMB + tid * 4] = c;
  if (cell == 0)
    *(float4*)&out[(size_t)row * ROW_TOK * EMB + tid * 4] =
        *(const float4*)&cls_w[tid * 4];
}

// ---------- gate MLP GEMM: 256x128 tile, 8 waves, contiguous-k b128 frags ----------
__global__ __launch_bounds__(512) void k_gate_gemm(
    const short* __restrict__ cnb, const short* __restrict__ w1t,
    const float* __restrict__ gate_b1, const float* __restrict__ gate_w2,
    float* __restrict__ gpart) {
  __shared__ short Asub[256 * 32];   // 16 KB
  __shared__ short Bsub[128 * 32];   // 8 KB
  const int tid = threadIdx.x;
  const int n0 = blockIdx.x * 256;
  const int h0 = blockIdx.y * 128;
  const int lane = tid & 63, w = tid >> 6;
  const int wr = w >> 1, wc = w & 1;       // wr 0..3 (m), wc 0..1 (h)
  const int r = lane & 15, g = lane >> 4;
  f32x4 acc[4][4];
  #pragma unroll
  for (int a = 0; a < 4; a++)
    #pragma unroll
    for (int b = 0; b < 4; b++) acc[a][b] = (f32x4)0.f;

  // staging slot s (16B): row = s>>2, chunk = s&3
  const int s0 = tid, s1 = tid + 512;
  const int ar0 = s0 >> 2, ac0 = (s0 & 3) * 8;
  const int ar1 = s1 >> 2, ac1 = (s1 & 3) * 8;

  for (int kk = 0; kk < EMB; kk += 32) {
    gload16(cnb + (size_t)(n0 + ar0) * EMB + kk + ac0, Asub + s0 * 8);
    gload16(cnb + (size_t)(n0 + ar1) * EMB + kk + ac1, Asub + s1 * 8);
    gload16(w1t + (size_t)(h0 + ar0) * EMB + kk + ac0, Bsub + s0 * 8);
    __syncthreads();
    bf16x8 fa[4], fb[4];
    #pragma unroll
    for (int fm = 0; fm < 4; fm++)
      fa[fm] = *(const bf16x8*)&Asub[(wr * 64 + fm * 16 + r) * 32 + g * 8];
    #pragma unroll
    for (int fn = 0; fn < 4; fn++)
      fb[fn] = *(const bf16x8*)&Bsub[(wc * 64 + fn * 16 + r) * 32 + g * 8];
    #pragma unroll
    for (int fm = 0; fm < 4; fm++)
      #pragma unroll
      for (int fn = 0; fn < 4; fn++)
        acc[fm][fn] = __builtin_amdgcn_mfma_f32_16x16x32_bf16(
            fa[fm], fb[fn], acc[fm][fn], 0, 0, 0);
    __syncthreads();
  }

  // epilogue: rowsum over this block's 128 h of relu(v + b1[h]) * w2[h]
  float rsum[4][4];
  #pragma unroll
  for (int fm = 0; fm < 4; fm++) {
    float rs[4] = {0.f, 0.f, 0.f, 0.f};
    #pragma unroll
    for (int fn = 0; fn < 4; fn++) {
      const int h = h0 + wc * 64 + fn * 16 + r;
      const float bv = gate_b1[h];
      const float wv = gate_w2[h];
      #pragma unroll
      for (int q = 0; q < 4; q++)
        rs[q] += fmaxf(acc[fm][fn][q] + bv, 0.f) * wv;
    }
    #pragma unroll
    for (int q = 0; q < 4; q++) {
      #pragma unroll
      for (int m = 1; m < 16; m <<= 1) rs[q] += __shfl_xor(rs[q], m);
      rsum[fm][q] = rs[q];
    }
  }
  // combine wc=0/1 waves via LDS (Asub is free), write partial once per n
  float* red = (float*)Asub;
  __syncthreads();
  if (wc == 1 && r == 0) {
    #pragma unroll
    for (int fm = 0; fm < 4; fm++)
      #pragma unroll
      for (int q = 0; q < 4; q++)
        red[wr * 64 + fm * 16 + g * 4 + q] = rsum[fm][q];
  }
  __syncthreads();
  if (wc == 0 && r == 0) {
    #pragma unroll
    for (int fm = 0; fm < 4; fm++)
      #pragma unroll
      for (int q = 0; q < 4; q++) {
        const int i = wr * 64 + fm * 16 + g * 4 + q;
        gpart[(size_t)blockIdx.y * NCELL + n0 + i] = rsum[fm][q] + red[i];
      }
  }
}

// ---------- per-row prefix sum: per-cell start offsets + row counts ----------
__global__ __launch_bounds__(256) void k_prefix(const int* __restrict__ cv_mask,
                                                int* __restrict__ cstart,
                                                int* __restrict__ cnt) {
  const int row = blockIdx.x, tid = threadIdx.x;
  __shared__ int ssum[256];
  int m[4];
  const int base = row * L_CV + tid * 4;
  int s = 0;
  #pragma unroll
  for (int i = 0; i < 4; i++) { m[i] = cv_mask[base + i]; s += m[i]; }
  ssum[tid] = s;
  __syncthreads();
  for (int off = 1; off < 256; off <<= 1) {
    int v = (tid >= off) ? ssum[tid - off] : 0;
    __syncthreads();
    ssum[tid] += v;
    __syncthreads();
  }
  if ((tid & 3) == 0) cstart[row * CELLS + (tid >> 2)] = ssum[tid] - s;
  if (tid == 255) cnt[row] = ssum[255];
}

// ---------- cv region: bx<64 compute cell tokens (incl. g); bx>=64 zero tail ----------
__global__ __launch_bounds__(192) void k_cv_cell(
    const int* __restrict__ cv_ids, const int* __restrict__ cv_mask,
    const int* __restrict__ cstart, const int* __restrict__ cnt,
    const float* __restrict__ word_emb, const float* __restrict__ gpart,
    const float* __restrict__ gate_b2, float* __restrict__ out) {
  const int bx = blockIdx.x, row = blockIdx.y, tid = threadIdx.x;
  const size_t rbase = (size_t)row * ROW_TOK * EMB;
  if (bx >= CELLS) {
    const int base = cnt[row] + (bx - CELLS) * 8;
    const float4 z = {0.f, 0.f, 0.f, 0.f};
    #pragma unroll
    for (int i = 0; i < 8; i++) {
      const int k = base + i;
      if (k < L_CV)
        *(float4*)&out[rbase + (size_t)(65 + k) * EMB + tid * 4] = z;
    }
    return;
  }
  const int cell = bx;
  const int n = row * CELLS + cell;
  float sg = gate_b2[0];
  #pragma unroll
  for (int j = 0; j < HBLK; j++) sg += gpart[(size_t)j * NCELL + n];
  const float gg = 1.f / (1.f + expf(-sg));
  const float4 cn = *(const float4*)&out[rbase + (size_t)(1 + cell) * EMB + tid * 4];
  float4 cg;
  cg.x = cn.x * gg; cg.y = cn.y * gg; cg.z = cn.z * gg; cg.w = cn.w * gg;
  const int* ids = cv_ids + n * CV_LEN;
  const int* msk = cv_mask + n * CV_LEN;
  int pos = cstart[n];
  #pragma unroll
  for (int j = 0; j < CV_LEN; j++) {
    if (msk[j]) {
      const float4 we = *(const float4*)&word_emb[(size_t)ids[j] * EMB + tid * 4];
      float4 v;
      v.x = we.x + cg.x; v.y = we.y + cg.y; v.z = we.z + cg.z; v.w = we.w + cg.w;
      *(float4*)&out[rbase + (size_t)(65 + pos) * EMB + tid * 4] = v;
      pos++;
    }
  }
}

extern "C" void kernel_launch(void* const* d_in, const int* in_sizes, int n_in,
                              void* d_out, int out_size, void* d_ws, size_t ws_size,
                              hipStream_t stream) {
  const int* cn_ids    = (const int*)d_in[0];
  const int* cn_mask   = (const int*)d_in[1];
  const int* c_types   = (const int*)d_in[2];
  const int* cv_ids    = (const int*)d_in[3];
  const int* cv_mask   = (const int*)d_in[4];
  const float* word_emb = (const float*)d_in[5];
  const float* type_emb = (const float*)d_in[6];
  const float* fuse_w1  = (const float*)d_in[7];
  const float* fuse_b1  = (const float*)d_in[8];
  const float* fuse_w2  = (const float*)d_in[9];
  const float* fuse_b2  = (const float*)d_in[10];
  const float* gate_w1  = (const float*)d_in[11];
  const float* gate_b1  = (const float*)d_in[12];
  const float* gate_w2  = (const float*)d_in[13];
  const float* gate_b2  = (const float*)d_in[14];
  const float* cls_w    = (const float*)d_in[15];

  char* ws = (char*)d_ws;
  float* fpart = (float*)(ws + OFF_FPART);
  float* fgate = (float*)(ws + OFF_FGATE);
  float* gpart = (float*)(ws + OFF_GPART);
  short* cnb   = (short*)(ws + OFF_CNB);
  short* w1t   = (short*)(ws + OFF_W1T);
  int*   cst   = (int*)(ws + OFF_CST);
  int*   cntp  = (int*)(ws + OFF_CNT);
  float* out   = (float*)d_out;

  k_fgate_acc<<<96, 512, 0, stream>>>(type_emb, fuse_w1, fuse_b1, fuse_w2, fpart);
  k_w1t<<<dim3(96, 24), 256, 0, stream>>>(gate_w1, w1t, fpart, fuse_b2, fgate);
  k_cn<<<NCELL, 192, 0, stream>>>(cn_ids, cn_mask, c_types, word_emb, type_emb,
                                  cls_w, fgate, cnb, out);
  k_gate_gemm<<<dim3(16, HBLK), 512, 0, stream>>>(cnb, w1t, gate_b1, gate_w2, gpart);
  k_prefix<<<64, 256, 0, stream>>>(cv_mask, cst, cntp);
  k_cv_cell<<<dim3(CELLS + 128, ROWS), 192, 0, stream>>>(cv_ids, cv_mask, cst,
                                                         cntp, word_emb, gpart,
                                                         gate_b2, out);
}

// Round 5
// 123.268 us; speedup vs baseline: 1.6355x; 1.0160x over previous
//
#include <hip/hip_runtime.h>
#include <hip/hip_bf16.h>

#define ROWS 64
#define CELLS 64
#define CN_LEN 8
#define CV_LEN 16
#define EMB 768
#define HID 3072
#define NCELL 4096
#define L_CV 1024
#define ROW_TOK 1089  /* 1 cls + 64 cn + 1024 cv */
#define HBLK 24       /* 3072/128 h-blocks in gate GEMM */

// ---- workspace layout (bytes), no zero-init required anywhere ----
#define OFF_FPART 0UL                             /* 96*8 f32 fgate partials */
#define OFF_FGATE (OFF_FPART + 96UL*8*4)          /* 8 f32 */
#define OFF_GPART (OFF_FGATE + 64UL)              /* 24*4096 f32 gemm partials */
#define OFF_CNB   (OFF_GPART + 24UL*4096*4)       /* 4096x768 bf16 */
#define OFF_W1T   (OFF_CNB + 4096UL*768*2)        /* 3072x768 bf16 (gate_w1^T) */
#define OFF_CST   (OFF_W1T + 3072UL*768*2)        /* 4096 int per-cell start */
#define OFF_CNT   (OFF_CST + 4096UL*4)            /* 64 int per-row count */

typedef __attribute__((ext_vector_type(8))) short bf16x8;
typedef __attribute__((ext_vector_type(4))) float f32x4;

static __device__ __forceinline__ short f2bf(float x) {
  unsigned u = __float_as_uint(x);
  unsigned r = (u + 0x7fffu + ((u >> 16) & 1u)) >> 16;
  return (short)r;
}

static __device__ __forceinline__ void gload16(const void* g, void* l) {
  __builtin_amdgcn_global_load_lds(
      (const __attribute__((address_space(1))) unsigned*)g,
      (__attribute__((address_space(3))) unsigned*)l, 16, 0, 0);
}

// ---------- fgate partials (blocks 0..95) + per-row cv prefix (blocks 96..159) ----------
__global__ __launch_bounds__(512) void k_fgate_acc(
    const float* __restrict__ type_emb, const float* __restrict__ fuse_w1,
    const float* __restrict__ fuse_b1, const float* __restrict__ fuse_w2,
    float* __restrict__ fpart, const int* __restrict__ cv_mask,
    int* __restrict__ cstart, int* __restrict__ cnt) {
  __shared__ float te[8 * EMB];      // 24 KB
  __shared__ float red[16][8][33];
  __shared__ int ssum[512];
  const int tid = threadIdx.x;
  if (blockIdx.x >= 96) {
    // ---- prefix scan over one row's 1024 cv_mask values ----
    const int row = blockIdx.x - 96;
    const int base = row * L_CV + tid * 2;
    const int m0 = cv_mask[base], m1 = cv_mask[base + 1];
    const int s = m0 + m1;
    ssum[tid] = s;
    __syncthreads();
    for (int off = 1; off < 512; off <<= 1) {
      int v = (tid >= off) ? ssum[tid - off] : 0;
      __syncthreads();
      ssum[tid] += v;
      __syncthreads();
    }
    if ((tid & 7) == 0) cstart[row * CELLS + (tid >> 3)] = ssum[tid] - s;
    if (tid == 511) cnt[row] = ssum[511];
    return;
  }
  // ---- fgate: 8-type register reuse, w1 read once ----
  for (int i = tid; i < 8 * EMB; i += 512) te[i] = type_emb[i];
  __syncthreads();
  const int hl = tid & 31, eg = tid >> 5;  // eg in 0..15, 48 e's each
  const int h = blockIdx.x * 32 + hl;
  float acc[8] = {0.f, 0.f, 0.f, 0.f, 0.f, 0.f, 0.f, 0.f};
  const float* wp = fuse_w1 + h;
  #pragma unroll 4
  for (int i = 0; i < 48; i++) {
    const int e = eg * 48 + i;
    const float wv = wp[(size_t)e * HID];
    #pragma unroll
    for (int t = 0; t < 8; t++) acc[t] += te[t * EMB + e] * wv;
  }
  #pragma unroll
  for (int t = 0; t < 8; t++) red[eg][t][hl] = acc[t];
  __syncthreads();
  if (tid < 256) {
    const int t = tid >> 5, h2 = tid & 31;
    float a = fuse_b1[blockIdx.x * 32 + h2];
    #pragma unroll
    for (int e2 = 0; e2 < 16; e2++) a += red[e2][t][h2];
    float v = fmaxf(a, 0.f) * fuse_w2[blockIdx.x * 32 + h2];
    #pragma unroll
    for (int m = 1; m < 32; m <<= 1) v += __shfl_xor(v, m);
    if (h2 == 0) fpart[blockIdx.x * 8 + t] = v;  // each slot written once
  }
}

// ---------- transpose + bf16 gate_w1 -> w1t; block(0,0) finalizes fgate ----------
__global__ __launch_bounds__(256) void k_w1t(const float* __restrict__ w1,
                                             short* __restrict__ w1t,
                                             const float* __restrict__ fpart,
                                             const float* __restrict__ fuse_b2,
                                             float* __restrict__ fgate) {
  __shared__ float tile[32][33];
  const int bx = blockIdx.x, by = blockIdx.y;  // bx: h tile, by: e tile
  const int tid = threadIdx.x;
  if (bx == 0 && by == 0 && tid < 8) {
    float s = fuse_b2[0];
    for (int j = 0; j < 96; j++) s += fpart[j * 8 + tid];
    fgate[tid] = 1.f / (1.f + expf(-s));
  }
  #pragma unroll
  for (int i = 0; i < 4; i++) {
    int idx = tid + i * 256;
    int rr = idx >> 5, cc = idx & 31;
    tile[rr][cc] = w1[(size_t)(by * 32 + rr) * HID + bx * 32 + cc];
  }
  __syncthreads();
  #pragma unroll
  for (int i = 0; i < 4; i++) {
    int idx = tid + i * 256;
    int rr = idx >> 5, cc = idx & 31;
    w1t[(size_t)(bx * 32 + rr) * EMB + by * 32 + cc] = f2bf(tile[cc][rr]);
  }
}

// ---------- cn_e: masked avg + type gate; write out cn region + cls ----------
__global__ __launch_bounds__(192) void k_cn(
    const int* __restrict__ cn_ids, const int* __restrict__ cn_mask,
    const int* __restrict__ c_types, const float* __restrict__ word_emb,
    const float* __restrict__ type_emb, const float* __restrict__ cls_w,
    const float* __restrict__ fgate, short* __restrict__ cnb,
    float* __restrict__ out) {
  const int n = blockIdx.x, tid = threadIdx.x;
  const int row = n >> 6, cell = n & 63;
  const int* ids = cn_ids + n * CN_LEN;
  const int* msk = cn_mask + n * CN_LEN;
  float4 s = {0.f, 0.f, 0.f, 0.f};
  int cnt = 0;
  #pragma unroll
  for (int j = 0; j < CN_LEN; j++) {
    if (msk[j]) {
      cnt++;
      const float4 v = *(const float4*)&word_emb[(size_t)ids[j] * EMB + tid * 4];
      s.x += v.x; s.y += v.y; s.z += v.z; s.w += v.w;
    }
  }
  const float inv = 1.f / (float)cnt;
  const int t = c_types[n];
  const float fg = fgate[t];
  const float4 d = *(const float4*)&type_emb[(size_t)t * EMB + tid * 4];
  float4 c;
  c.x = s.x * inv + d.x * fg;
  c.y = s.y * inv + d.y * fg;
  c.z = s.z * inv + d.z * fg;
  c.w = s.w * inv + d.w * fg;
  short4 b;
  b.x = f2bf(c.x); b.y = f2bf(c.y); b.z = f2bf(c.z); b.w = f2bf(c.w);
  *(short4*)&cnb[(size_t)n * EMB + tid * 4] = b;
  *(float4*)&out[(size_t)row * ROW_TOK * EMB + (size_t)(1 + cell) * EMB + tid * 4] = c;
  if (cell == 0)
    *(float4*)&out[(size_t)row * ROW_TOK * EMB + tid * 4] =
        *(const float4*)&cls_w[tid * 4];
}

// ---------- gate MLP GEMM: 128x128, double-buffered 2-phase, XCD swizzle ----------
__global__ __launch_bounds__(256) void k_gate_gemm(
    const short* __restrict__ cnb, const short* __restrict__ w1t,
    const float* __restrict__ gate_b1, const float* __restrict__ gate_w2,
    float* __restrict__ gpart) {
  __shared__ short Asub[2][128 * 32];   // 2 x 8 KB
  __shared__ short Bsub[2][128 * 32];   // 2 x 8 KB
  const int tid = threadIdx.x;
  // bijective XCD swizzle: 768 blocks, 96 consecutive per XCD -> same-by chunks
  const int orig = blockIdx.x;
  const int wgid = (orig & 7) * 96 + (orig >> 3);
  const int bx = wgid & 31, by = wgid >> 5;   // bx: n-tile 0..31, by: h-tile 0..23
  const int n0 = bx * 128, h0 = by * 128;
  const int lane = tid & 63, w = tid >> 6;
  const int wr = w >> 1, wc = w & 1;
  const int r = lane & 15, g = lane >> 4;
  f32x4 acc[4][4];
  #pragma unroll
  for (int a = 0; a < 4; a++)
    #pragma unroll
    for (int b = 0; b < 4; b++) acc[a][b] = (f32x4)0.f;

  // staging slot s (16B): row = s>>2, chunk = s&3
  const int s0 = tid, s1 = tid + 256;
  const int ar0 = s0 >> 2, ac0 = (s0 & 3) * 8;
  const int ar1 = s1 >> 2, ac1 = (s1 & 3) * 8;
  const short* aB = cnb + (size_t)n0 * EMB;
  const short* bB = w1t + (size_t)h0 * EMB;

#define STAGE(buf, kk)                                                  \
  do {                                                                  \
    gload16(aB + (size_t)ar0 * EMB + (kk) + ac0, &Asub[buf][s0 * 8]);   \
    gload16(aB + (size_t)ar1 * EMB + (kk) + ac1, &Asub[buf][s1 * 8]);   \
    gload16(bB + (size_t)ar0 * EMB + (kk) + ac0, &Bsub[buf][s0 * 8]);   \
    gload16(bB + (size_t)ar1 * EMB + (kk) + ac1, &Bsub[buf][s1 * 8]);   \
  } while (0)

#define COMPUTE(buf)                                                          \
  do {                                                                        \
    bf16x8 fa[4], fb[4];                                                      \
    _Pragma("unroll")                                                         \
    for (int fm = 0; fm < 4; fm++)                                            \
      fa[fm] = *(const bf16x8*)&Asub[buf][(wr * 64 + fm * 16 + r) * 32 + g * 8]; \
    _Pragma("unroll")                                                         \
    for (int fn = 0; fn < 4; fn++)                                            \
      fb[fn] = *(const bf16x8*)&Bsub[buf][(wc * 64 + fn * 16 + r) * 32 + g * 8]; \
    _Pragma("unroll")                                                         \
    for (int fm = 0; fm < 4; fm++)                                            \
      _Pragma("unroll")                                                       \
      for (int fn = 0; fn < 4; fn++)                                          \
        acc[fm][fn] = __builtin_amdgcn_mfma_f32_16x16x32_bf16(                \
            fa[fm], fb[fn], acc[fm][fn], 0, 0, 0);                            \
  } while (0)

  STAGE(0, 0);
  __syncthreads();            // drains vmcnt -> buf0 ready
  int cur = 0;
  for (int t = 0; t < 23; t++) {
    STAGE(cur ^ 1, (t + 1) * 32);  // prefetch next K-step (hidden under MFMA)
    COMPUTE(cur);
    __syncthreads();          // drains prefetch + guards buffer reuse
    cur ^= 1;
  }
  COMPUTE(cur);

  // epilogue: rowsum over this block's 128 h of relu(v + b1[h]) * w2[h]
  float rsum[4][4];
  #pragma unroll
  for (int fm = 0; fm < 4; fm++) {
    float rs[4] = {0.f, 0.f, 0.f, 0.f};
    #pragma unroll
    for (int fn = 0; fn < 4; fn++) {
      const int h = h0 + wc * 64 + fn * 16 + r;
      const float bv = gate_b1[h];
      const float wv = gate_w2[h];
      #pragma unroll
      for (int q = 0; q < 4; q++)
        rs[q] += fmaxf(acc[fm][fn][q] + bv, 0.f) * wv;
    }
    #pragma unroll
    for (int q = 0; q < 4; q++) {
      #pragma unroll
      for (int m = 1; m < 16; m <<= 1) rs[q] += __shfl_xor(rs[q], m);
      rsum[fm][q] = rs[q];
    }
  }
  // combine wc=0/1 waves via LDS, write partial once per n
  float* red = (float*)&Asub[0][0];
  __syncthreads();
  if (wc == 1 && r == 0) {
    #pragma unroll
    for (int fm = 0; fm < 4; fm++)
      #pragma unroll
      for (int q = 0; q < 4; q++)
        red[wr * 64 + fm * 16 + g * 4 + q] = rsum[fm][q];
  }
  __syncthreads();
  if (wc == 0 && r == 0) {
    #pragma unroll
    for (int fm = 0; fm < 4; fm++)
      #pragma unroll
      for (int q = 0; q < 4; q++) {
        const int i = wr * 64 + fm * 16 + g * 4 + q;
        gpart[(size_t)by * NCELL + n0 + i] = rsum[fm][q] + red[i];
      }
  }
#undef STAGE
#undef COMPUTE
}

// ---------- cv region: bx<64 compute cell tokens (incl. g); bx>=64 zero tail ----------
__global__ __launch_bounds__(192) void k_cv_cell(
    const int* __restrict__ cv_ids, const int* __restrict__ cv_mask,
    const int* __restrict__ cstart, const int* __restrict__ cnt,
    const float* __restrict__ word_emb, const float* __restrict__ gpart,
    const float* __restrict__ gate_b2, float* __restrict__ out) {
  const int bx = blockIdx.x, row = blockIdx.y, tid = threadIdx.x;
  const size_t rbase = (size_t)row * ROW_TOK * EMB;
  if (bx >= CELLS) {
    const int base = cnt[row] + (bx - CELLS) * 8;
    const float4 z = {0.f, 0.f, 0.f, 0.f};
    #pragma unroll
    for (int i = 0; i < 8; i++) {
      const int k = base + i;
      if (k < L_CV)
        *(float4*)&out[rbase + (size_t)(65 + k) * EMB + tid * 4] = z;
    }
    return;
  }
  const int cell = bx;
  const int n = row * CELLS + cell;
  float sg = gate_b2[0];
  #pragma unroll
  for (int j = 0; j < HBLK; j++) sg += gpart[(size_t)j * NCELL + n];
  const float gg = 1.f / (1.f + expf(-sg));
  const float4 cn = *(const float4*)&out[rbase + (size_t)(1 + cell) * EMB + tid * 4];
  float4 cg;
  cg.x = cn.x * gg; cg.y = cn.y * gg; cg.z = cn.z * gg; cg.w = cn.w * gg;
  const int* ids = cv_ids + n * CV_LEN;
  const int* msk = cv_mask + n * CV_LEN;
  int pos = cstart[n];
  #pragma unroll
  for (int j = 0; j < CV_LEN; j++) {
    if (msk[j]) {
      const float4 we = *(const float4*)&word_emb[(size_t)ids[j] * EMB + tid * 4];
      float4 v;
      v.x = we.x + cg.x; v.y = we.y + cg.y; v.z = we.z + cg.z; v.w = we.w + cg.w;
      *(float4*)&out[rbase + (size_t)(65 + pos) * EMB + tid * 4] = v;
      pos++;
    }
  }
}

extern "C" void kernel_launch(void* const* d_in, const int* in_sizes, int n_in,
                              void* d_out, int out_size, void* d_ws, size_t ws_size,
                              hipStream_t stream) {
  const int* cn_ids    = (const int*)d_in[0];
  const int* cn_mask   = (const int*)d_in[1];
  const int* c_types   = (const int*)d_in[2];
  const int* cv_ids    = (const int*)d_in[3];
  const int* cv_mask   = (const int*)d_in[4];
  const float* word_emb = (const float*)d_in[5];
  const float* type_emb = (const float*)d_in[6];
  const float* fuse_w1  = (const float*)d_in[7];
  const float* fuse_b1  = (const float*)d_in[8];
  const float* fuse_w2  = (const float*)d_in[9];
  const float* fuse_b2  = (const float*)d_in[10];
  const float* gate_w1  = (const float*)d_in[11];
  const float* gate_b1  = (const float*)d_in[12];
  const float* gate_w2  = (const float*)d_in[13];
  const float* gate_b2  = (const float*)d_in[14];
  const float* cls_w    = (const float*)d_in[15];

  char* ws = (char*)d_ws;
  float* fpart = (float*)(ws + OFF_FPART);
  float* fgate = (float*)(ws + OFF_FGATE);
  float* gpart = (float*)(ws + OFF_GPART);
  short* cnb   = (short*)(ws + OFF_CNB);
  short* w1t   = (short*)(ws + OFF_W1T);
  int*   cst   = (int*)(ws + OFF_CST);
  int*   cntp  = (int*)(ws + OFF_CNT);
  float* out   = (float*)d_out;

  k_fgate_acc<<<160, 512, 0, stream>>>(type_emb, fuse_w1, fuse_b1, fuse_w2,
                                       fpart, cv_mask, cst, cntp);
  k_w1t<<<dim3(96, 24), 256, 0, stream>>>(gate_w1, w1t, fpart, fuse_b2, fgate);
  k_cn<<<NCELL, 192, 0, stream>>>(cn_ids, cn_mask, c_types, word_emb, type_emb,
                                  cls_w, fgate, cnb, out);
  k_gate_gemm<<<768, 256, 0, stream>>>(cnb, w1t, gate_b1, gate_w2, gpart);
  k_cv_cell<<<dim3(CELLS + 128, ROWS), 192, 0, stream>>>(cv_ids, cv_mask, cst,
                                                         cntp, word_emb, gpart,
                                                         gate_b2, out);
}